// Round 5
// baseline (333.451 us; speedup 1.0000x reference)
//
#include <hip/hip_runtime.h>

// CompositeValueNoise R5: 512-bucket global counting sort + fused in-LDS
// fine sort (1/32^3 sub-cells) in the main kernel so each wave's gathers
// land in 1-2 fine cells (~4x fewer distinct cache lines per gather inst).

#define NB 512                 // 8^3 coarse buckets
#define PTS_PER_BLK 4096
#define CHUNK 32
#define SC_THREADS 1024
#define SC_PPT (PTS_PER_BLK / SC_THREADS)   // 4
#define H_THREADS 256
#define H_PPT (PTS_PER_BLK / H_THREADS)     // 16
#define TILE 4608              // main-kernel LDS tile (mean seg 3906, sd ~62)

__device__ __forceinline__ int bucket_of(float px, float py, float pz) {
    int ix = min(max((int)(px * 8.0f), 0), 7);
    int iy = min(max((int)(py * 8.0f), 0), 7);
    int iz = min(max((int)(pz * 8.0f), 0), 7);
    return (ix * 8 + iy) * 8 + iz;
}

__global__ void __launch_bounds__(H_THREADS)
cvn_hist(const float* __restrict__ x, int* __restrict__ P, int n) {
    __shared__ int cnt[NB];
    int t = threadIdx.x;
    for (int q = t; q < NB; q += H_THREADS) cnt[q] = 0;
    __syncthreads();
    int base = blockIdx.x * PTS_PER_BLK;
    for (int k = 0; k < H_PPT; ++k) {
        int i = base + k * H_THREADS + t;
        if (i < n)
            atomicAdd(&cnt[bucket_of(x[3 * i], x[3 * i + 1], x[3 * i + 2])], 1);
    }
    __syncthreads();
    int* Pb = P + (size_t)blockIdx.x * NB;
    for (int q = t; q < NB; q += H_THREADS) Pb[q] = cnt[q];
}

__global__ void __launch_bounds__(256)
cvn_scan_a(const int* __restrict__ P, int* __restrict__ S, int nblk) {
    int q = blockIdx.x * 256 + threadIdx.x;
    int c = blockIdx.y;
    int b0 = c * CHUNK, b1 = min(b0 + CHUNK, nblk);
    int s = 0;
    for (int b = b0; b < b1; ++b) s += P[(size_t)b * NB + q];
    S[(size_t)c * NB + q] = s;
}

// After this kernel: S[c][q] = Texcl[q] + exclusive chunk prefix. In
// particular S[0][q] = Texcl[q] = global base of bucket q.
__global__ void __launch_bounds__(NB)
cvn_scan_b(int* __restrict__ S, int nch) {
    __shared__ int part[NB];
    int t = threadIdx.x;
    int acc = 0;
    for (int c = 0; c < nch; ++c) {
        int v = S[(size_t)c * NB + t];
        S[(size_t)c * NB + t] = acc;
        acc += v;
    }
    part[t] = acc;
    __syncthreads();
    for (int off = 1; off < NB; off <<= 1) {
        int v = (t >= off) ? part[t - off] : 0;
        __syncthreads();
        if (t >= off) part[t] += v;
        __syncthreads();
    }
    int texcl = (t == 0) ? 0 : part[t - 1];
    for (int c = 0; c < nch; ++c) S[(size_t)c * NB + t] += texcl;
}

__global__ void __launch_bounds__(256)
cvn_scan_c(int* __restrict__ P, const int* __restrict__ S, int nblk) {
    int q = blockIdx.x * 256 + threadIdx.x;
    int c = blockIdx.y;
    int b0 = c * CHUNK, b1 = min(b0 + CHUNK, nblk);
    int run = S[(size_t)c * NB + q];
    for (int b = b0; b < b1; ++b) {
        int v = P[(size_t)b * NB + q];
        P[(size_t)b * NB + q] = run;
        run += v;
    }
}

__global__ void __launch_bounds__(SC_THREADS)
cvn_scatter(const float* __restrict__ x, const int* __restrict__ P,
            float4* __restrict__ sorted, int* __restrict__ rank,
            int n, int write_rank) {
    __shared__ int cnt[NB];
    __shared__ int place[NB];
    __shared__ int Pb[NB];
    __shared__ int sc[NB];
    __shared__ float4 payload[PTS_PER_BLK];
    __shared__ unsigned short bkt[PTS_PER_BLK];
    int t = threadIdx.x, b = blockIdx.x;
    int base = b * PTS_PER_BLK;
    if (t < NB) {
        cnt[t] = 0; place[t] = 0;
        Pb[t] = P[(size_t)b * NB + t];
    }
    __syncthreads();

    float px[SC_PPT], py[SC_PPT], pz[SC_PPT];
    int qq[SC_PPT];
    #pragma unroll
    for (int k = 0; k < SC_PPT; ++k) {
        int i = base + k * SC_THREADS + t;
        if (i < n) {
            px[k] = x[3 * i]; py[k] = x[3 * i + 1]; pz[k] = x[3 * i + 2];
            qq[k] = bucket_of(px[k], py[k], pz[k]);
            atomicAdd(&cnt[qq[k]], 1);
        } else qq[k] = -1;
    }
    __syncthreads();

    if (t < NB) sc[t] = cnt[t];
    __syncthreads();
    for (int off = 1; off < NB; off <<= 1) {
        int v = (t < NB && t >= off) ? sc[t - off] : 0;
        __syncthreads();
        if (t < NB && t >= off) sc[t] += v;
        __syncthreads();
    }
    if (t < NB) cnt[t] = (t == 0) ? 0 : sc[t - 1];
    __syncthreads();

    #pragma unroll
    for (int k = 0; k < SC_PPT; ++k) {
        if (qq[k] >= 0) {
            int q = qq[k];
            int lp = atomicAdd(&place[q], 1);
            int slot = cnt[q] + lp;
            int i = base + k * SC_THREADS + t;
            payload[slot] = make_float4(px[k], py[k], pz[k], __int_as_float(i));
            bkt[slot] = (unsigned short)q;
            if (write_rank) rank[i] = Pb[q] + lp;
        }
    }
    __syncthreads();

    int total = min(n - base, PTS_PER_BLK);
    #pragma unroll
    for (int k = 0; k < SC_PPT; ++k) {
        int j = k * SC_THREADS + t;
        if (j < total) {
            int q = bkt[j];
            sorted[Pb[q] + (j - cnt[q])] = payload[j];
        }
    }
}

__device__ __forceinline__ float4 lerp4(float4 a, float4 b, float w) {
    return make_float4(a.x + w * (b.x - a.x),
                       a.y + w * (b.y - a.y),
                       a.z + w * (b.z - a.z),
                       a.w + w * (b.w - a.w));
}

template <int RES>
__device__ __forceinline__ float4 level_val(const float4* __restrict__ V,
                                            float px, float py, float pz) {
    constexpr int S = RES + 1;
    float xs = fmodf(px * (float)RES, (float)RES);
    float ys = fmodf(py * (float)RES, (float)RES);
    float zs = fmodf(pz * (float)RES, (float)RES);
    float fx = floorf(xs), fy = floorf(ys), fz = floorf(zs);
    float tx = xs - fx, ty = ys - fy, tz = zs - fz;
    int ix = (int)fx, iy = (int)fy, iz = (int)fz;

    float wx = (3.0f - 2.0f * tx) * tx * tx;
    float wy = (3.0f - 2.0f * ty) * ty * ty;
    float wz = (3.0f - 2.0f * tz) * tz * tz;

    int base = (ix * S + iy) * S + iz;
    const float4* p0 = V + base;
    const float4* p1 = p0 + S * S;

    float4 c000 = p0[0];
    float4 c001 = p0[1];
    float4 c010 = p0[S];
    float4 c011 = p0[S + 1];
    float4 c100 = p1[0];
    float4 c101 = p1[1];
    float4 c110 = p1[S];
    float4 c111 = p1[S + 1];

    float4 m00 = lerp4(c000, c100, wx);
    float4 m01 = lerp4(c001, c101, wx);
    float4 m10 = lerp4(c010, c110, wx);
    float4 m11 = lerp4(c011, c111, wx);
    float4 n0  = lerp4(m00, m10, wy);
    float4 n1  = lerp4(m01, m11, wy);
    return lerp4(n0, n1, wz);
}

__device__ __forceinline__ float4 composite(const float4* __restrict__ V16,
                                            const float4* __restrict__ V32,
                                            const float4* __restrict__ V64,
                                            const float4* __restrict__ V128,
                                            float px, float py, float pz) {
    float4 acc = level_val<16>(V16, px, py, pz);
    float4 v;
    v = level_val<32>(V32, px, py, pz);
    acc.x += 0.5f * v.x; acc.y += 0.5f * v.y; acc.z += 0.5f * v.z; acc.w += 0.5f * v.w;
    v = level_val<64>(V64, px, py, pz);
    acc.x += 0.25f * v.x; acc.y += 0.25f * v.y; acc.z += 0.25f * v.z; acc.w += 0.25f * v.w;
    v = level_val<128>(V128, px, py, pz);
    acc.x += 0.125f * v.x; acc.y += 0.125f * v.y; acc.z += 0.125f * v.z; acc.w += 0.125f * v.w;
    return acc;
}

// Main kernel R5: one WG per coarse bucket; local counting sort by 1/32^3
// sub-cell so each wave gathers within 1-2 fine cells. Writes tmp[] in
// sorted-position order (dense per-segment window -> full-line L2 evicts).
__global__ void __launch_bounds__(1024)
cvn_main2(const float4* __restrict__ sorted, const int* __restrict__ Tbase,
          const float4* __restrict__ V16, const float4* __restrict__ V32,
          const float4* __restrict__ V64, const float4* __restrict__ V128,
          float4* __restrict__ tmp, int n) {
    __shared__ float4 pts[TILE];            // 73728 B
    __shared__ unsigned short keys[TILE];   //  9216 B
    __shared__ unsigned short perm[TILE];   //  9216 B
    __shared__ int bins[64];
    int t = threadIdx.x, q = blockIdx.x;
    int base = Tbase[q];
    int end  = (q == NB - 1) ? n : Tbase[q + 1];
    int len  = end - base;
    int lenT = min(len, TILE);

    if (t < 64) bins[t] = 0;
    __syncthreads();

    // Load tile + fine-key histogram (1/32 sub-cell within the 1/8 cell).
    for (int p = t; p < lenT; p += 1024) {
        float4 pt = sorted[base + p];
        pts[p] = pt;
        int kx = min(max((int)(pt.x * 32.0f), 0), 31) & 3;
        int ky = min(max((int)(pt.y * 32.0f), 0), 31) & 3;
        int kz = min(max((int)(pt.z * 32.0f), 0), 31) & 3;
        int key = (kx * 4 + ky) * 4 + kz;
        keys[p] = (unsigned short)key;
        atomicAdd(&bins[key], 1);
    }
    __syncthreads();

    if (t == 0) {
        int s = 0;
        for (int k = 0; k < 64; ++k) { int c = bins[k]; bins[k] = s; s += c; }
    }
    __syncthreads();

    for (int p = t; p < lenT; p += 1024) {
        int slot = atomicAdd(&bins[keys[p]], 1);
        perm[slot] = (unsigned short)p;
    }
    __syncthreads();

    // Process in fine-sorted order; write to sorted-position slot in tmp.
    for (int p = t; p < lenT; p += 1024) {
        int j = perm[p];
        float4 pt = pts[j];
        tmp[base + j] = composite(V16, V32, V64, V128, pt.x, pt.y, pt.z);
    }
    // Overflow (len > TILE): ~never (11 sigma), processed unsorted.
    for (int p = lenT + t; p < len; p += 1024) {
        float4 pt = sorted[base + p];
        tmp[base + p] = composite(V16, V32, V64, V128, pt.x, pt.y, pt.z);
    }
}

// Fallback main (mid ws tier): sorted coarse order, scattered out write.
__global__ void __launch_bounds__(256)
cvn_main(const float4* __restrict__ sorted,
         const float4* __restrict__ V16, const float4* __restrict__ V32,
         const float4* __restrict__ V64, const float4* __restrict__ V128,
         float4* __restrict__ outbuf, int n, int nblocks) {
    int nb8 = nblocks >> 3;
    int c = (blockIdx.x & 7) * nb8 + (blockIdx.x >> 3);
    int j = c * 256 + (int)threadIdx.x;
    if (j >= n) return;
    float4 p = sorted[j];
    outbuf[__float_as_int(p.w)] = composite(V16, V32, V64, V128, p.x, p.y, p.z);
}

__global__ void __launch_bounds__(256)
cvn_permute(const float4* __restrict__ tmp, const int* __restrict__ rank,
            float4* __restrict__ out, int n) {
    int i = blockIdx.x * 256 + (int)threadIdx.x;
    if (i >= n) return;
    out[i] = tmp[rank[i]];
}

__global__ void __launch_bounds__(256)
cvn_direct(const float* __restrict__ x,
           const float4* __restrict__ V16, const float4* __restrict__ V32,
           const float4* __restrict__ V64, const float4* __restrict__ V128,
           float4* __restrict__ out, int n) {
    int i = blockIdx.x * blockDim.x + threadIdx.x;
    if (i >= n) return;
    out[i] = composite(V16, V32, V64, V128, x[3 * i], x[3 * i + 1], x[3 * i + 2]);
}

extern "C" void kernel_launch(void* const* d_in, const int* in_sizes, int n_in,
                              void* d_out, int out_size, void* d_ws, size_t ws_size,
                              hipStream_t stream) {
    const float*  x    = (const float*)d_in[0];
    const float4* V16  = (const float4*)d_in[1];
    const float4* V32  = (const float4*)d_in[2];
    const float4* V64  = (const float4*)d_in[3];
    const float4* V128 = (const float4*)d_in[4];
    float4* out = (float4*)d_out;

    int n = in_sizes[0] / 3;
    int nblk = (n + PTS_PER_BLK - 1) / PTS_PER_BLK;
    int nch  = (nblk + CHUNK - 1) / CHUNK;

    auto align256 = [](size_t v) { return (v + 255) & ~(size_t)255; };
    size_t offP      = 0;
    size_t offS      = align256(offP + (size_t)nblk * NB * sizeof(int));
    size_t offSorted = align256(offS + (size_t)nch * NB * sizeof(int));
    size_t offRank   = align256(offSorted + (size_t)n * sizeof(float4));
    size_t offTmp    = align256(offRank + (size_t)n * sizeof(int));
    size_t needFull  = offTmp + (size_t)n * sizeof(float4);
    size_t needMid   = offRank;

    int grid256 = (n + 255) / 256;
    int nblocks = ((grid256 + 7) / 8) * 8;

    if (ws_size >= needMid) {
        int*    P      = (int*)((char*)d_ws + offP);
        int*    S      = (int*)((char*)d_ws + offS);
        float4* sorted = (float4*)((char*)d_ws + offSorted);
        bool full = (ws_size >= needFull);
        int*    rank = full ? (int*)((char*)d_ws + offRank) : nullptr;
        float4* tmp  = full ? (float4*)((char*)d_ws + offTmp) : nullptr;

        cvn_hist<<<nblk, H_THREADS, 0, stream>>>(x, P, n);
        cvn_scan_a<<<dim3(NB / 256, nch), 256, 0, stream>>>(P, S, nblk);
        cvn_scan_b<<<1, NB, 0, stream>>>(S, nch);
        cvn_scan_c<<<dim3(NB / 256, nch), 256, 0, stream>>>(P, S, nblk);
        cvn_scatter<<<nblk, SC_THREADS, 0, stream>>>(x, P, sorted, rank, n,
                                                     full ? 1 : 0);
        if (full) {
            // S row 0 holds Texcl[q] (global bucket bases).
            cvn_main2<<<NB, 1024, 0, stream>>>(sorted, S, V16, V32, V64, V128,
                                               tmp, n);
            cvn_permute<<<grid256, 256, 0, stream>>>(tmp, rank, out, n);
        } else {
            cvn_main<<<nblocks, 256, 0, stream>>>(sorted, V16, V32, V64, V128,
                                                  out, n, nblocks);
        }
    } else {
        cvn_direct<<<grid256, 256, 0, stream>>>(x, V16, V32, V64, V128, out, n);
    }
}